// Round 7
// baseline (505.768 us; speedup 1.0000x reference)
//
#include <hip/hip_runtime.h>
#include <cstdint>

#define BB 8192
#define TT 50
#define FF 24

typedef __attribute__((ext_vector_type(8))) short short8;
typedef __attribute__((ext_vector_type(4))) float f32x4;

__device__ __forceinline__ float sigf(float x){ return 1.0f/(1.0f + __expf(-x)); }

// 2-way bf16 split (truncation): w ~= s1 + s2 to ~16 mantissa bits
__device__ __forceinline__ void split2(float w, unsigned short& s1, unsigned short& s2){
  unsigned b = __float_as_uint(w);
  s1 = (unsigned short)(b >> 16);
  float r = w - __uint_as_float(b & 0xFFFF0000u);
  s2 = (unsigned short)(__float_as_uint(r) >> 16);
}

#define MFMA(A,B,C) __builtin_amdgcn_mfma_f32_16x16x32_bf16((A),(B),(C),0,0,0)
#define PROD3(C,A1,A2,Bq1,Bq2) \
  C = MFMA(A1,Bq1,C); C = MFMA(A1,Bq2,C); C = MFMA(A2,Bq1,C);

// Round 7: gate-aligned MFMA column maps put all 4 gate pre-activations of a
// channel in ONE wave -> gates computed from C-fragments via __shfl_xor, no z
// LDS round-trip, ONE barrier per time-step. State (x/h1/h2/h3) bf16-split
// planes are parity double-buffered: segment s reads parity s&1, writes s&1^1.
// 256 blocks x 512 thr = 1 block/CU, 2 independent 16-row groups per block
// (latency hiding without the round-6 2-block VGPR cap -> no spill).
__global__ __launch_bounds__(512) void ae_k(
    const float* __restrict__ x,
    const float* __restrict__ W1, const float* __restrict__ U1, const float* __restrict__ b1,
    const float* __restrict__ W2, const float* __restrict__ U2, const float* __restrict__ b2,
    const float* __restrict__ W3, const float* __restrict__ U3, const float* __restrict__ b3,
    const float* __restrict__ Wd, const float* __restrict__ bd,
    float* __restrict__ out)
{
  constexpr int AS1 = 104, AS2 = 40, AS3 = 72;
  // [group][parity][plane][16*stride]
  __shared__ unsigned short asp1[2][2][2][16*AS1];  // [x(24)|h1(64)|pad]
  __shared__ unsigned short asp2[2][2][2][16*AS2];  // [h2(32)|pad]
  __shared__ unsigned short asp3[2][2][2][16*AS3];  // [h3(64)|pad]

  const int tid = threadIdx.x, wave = tid>>6, lane = tid&63;
  const int quad = lane>>4, li = lane&15;
  const int b0 = blockIdx.x*32;

  // gate-aligned column maps
  const int colA0 = ((li>>3)    )*64 + wave*8 + (li&7);  // ntile0: gate i/f
  const int colA1 = (2 + (li>>3))*64 + wave*8 + (li&7);  // ntile1: gate g/o
  const int col2  = (li>>2)*32 + wave*4 + (li&3);        // N=128 map

  // ---- phase-A resident B-fragments ----
  short8 B1a[2][3], B1b[2][3];
#pragma unroll
  for (int nt=0; nt<2; ++nt)
#pragma unroll
  for (int ks=0; ks<3; ++ks){
    short8 v1, v2;
#pragma unroll
    for (int j=0; j<8; ++j){
      const int k = ks*32 + quad*8 + j;
      const int c = nt ? colA1 : colA0;
      float w = (k<24) ? W1[k*256+c] : ((k<88) ? U1[(k-24)*256+c] : 0.f);
      unsigned short s1,s2; split2(w,s1,s2);
      v1[j]=(short)s1; v2[j]=(short)s2;
    }
    B1a[nt][ks]=v1; B1b[nt][ks]=v2;
  }
  short8 B2a[3], B2b[3];
#pragma unroll
  for (int ks=0; ks<3; ++ks){
    short8 v1, v2;
#pragma unroll
    for (int j=0; j<8; ++j){
      const int k = ks*32 + quad*8 + j;
      float w = (k<64) ? W2[k*128+col2] : U2[(k-64)*128+col2];
      unsigned short s1,s2; split2(w,s1,s2);
      v1[j]=(short)s1; v2[j]=(short)s2;
    }
    B2a[ks]=v1; B2b[ks]=v2;
  }
  const float bi1A = b1[colA0], bi1B = b1[colA1], bi2 = b2[col2];

  // zero all state planes (h initial states + pads)
  { unsigned* p = (unsigned*)asp1;
    for (int i=tid; i<2*2*2*16*AS1/2; i+=512) p[i]=0u;
    p = (unsigned*)asp2;
    for (int i=tid; i<2*2*2*16*AS2/2; i+=512) p[i]=0u;
    p = (unsigned*)asp3;
    for (int i=tid; i<2*2*2*16*AS3/2; i+=512) p[i]=0u; }
  __syncthreads();
  // stage x(0) into parity 1 (read parity of segment s=-1)
  if (tid < 384){
    const int xr = tid/12, xf = (tid - xr*12)*2;
    const int xg = xr>>4, row = xr&15;
    float2 v = *(const float2*)&x[((size_t)(b0+xr)*TT + 0)*FF + xf];
    unsigned short a1,a2,d1,d2; split2(v.x,a1,a2); split2(v.y,d1,d2);
    *(unsigned*)&asp1[xg][1][0][row*AS1+xf] = (unsigned)a1 | ((unsigned)d1<<16);
    *(unsigned*)&asp1[xg][1][1][row*AS1+xf] = (unsigned)a2 | ((unsigned)d2<<16);
  }
  float c1s[2][4] = {}, c2s[2][4] = {};
  __syncthreads();

  // =================== Phase A: L1+L2, ONE barrier per t ===================
#pragma unroll 1
  for (int s=-1; s<TT; ++s){
    const int rp = s & 1, wp = rp ^ 1;
    // x(s+2) prefetch (global) early in segment
    float2 xv; int xg=0, xrow=0, xf=0;
    const bool doX = (s+2 < TT) && (tid < 384);
    if (doX){
      const int xr = tid/12; xf = (tid - xr*12)*2; xg = xr>>4; xrow = xr&15;
      xv = *(const float2*)&x[((size_t)(b0+xr)*TT + (s+2))*FF + xf];
    }
    const bool doL2 = (s >= 0), doL1 = (s < TT-1);
    f32x4 C2[2], C0[2], C1[2];
#pragma unroll
    for (int g=0; g<2; ++g){
      if (doL2){
        f32x4 c = {bi2,bi2,bi2,bi2};
#pragma unroll
        for (int ks=0; ks<2; ++ks){
          const int ab = li*AS1 + 24 + ks*32 + quad*8;
          short8 A1 = *(const short8*)&asp1[g][rp][0][ab];
          short8 A2 = *(const short8*)&asp1[g][rp][1][ab];
          PROD3(c, A1,A2, B2a[ks],B2b[ks])
        }
        { const int ab = li*AS2 + quad*8;
          short8 A1 = *(const short8*)&asp2[g][rp][0][ab];
          short8 A2 = *(const short8*)&asp2[g][rp][1][ab];
          PROD3(c, A1,A2, B2a[2],B2b[2]) }
        C2[g] = c;
      }
      if (doL1){
        f32x4 c0 = {bi1A,bi1A,bi1A,bi1A}, c1 = {bi1B,bi1B,bi1B,bi1B};
#pragma unroll
        for (int ks=0; ks<3; ++ks){
          const int ab = li*AS1 + ks*32 + quad*8;
          short8 A1 = *(const short8*)&asp1[g][rp][0][ab];
          short8 A2 = *(const short8*)&asp1[g][rp][1][ab];
          PROD3(c0, A1,A2, B1a[0][ks],B1b[0][ks])
          PROD3(c1, A1,A2, B1a[1][ks],B1b[1][ks])
        }
        C0[g]=c0; C1[g]=c1;
      }
    }
    // in-register gates
#pragma unroll
    for (int g=0; g<2; ++g){
      if (doL2){  // gate2(s): zi=C2, zf=xor4, zg=xor8, zo=xor12; lanes li<4
        float zfv[4], zgv[4], zov[4];
#pragma unroll
        for (int i2=0;i2<4;++i2){
          zfv[i2]=__shfl_xor(C2[g][i2],4);
          zgv[i2]=__shfl_xor(C2[g][i2],8);
          zov[i2]=__shfl_xor(C2[g][i2],12);
        }
        if (li < 4){
          const int ch = wave*4 + li;
#pragma unroll
          for (int i2=0;i2<4;++i2){
            const int row = quad*4+i2;
            const float ig=sigf(C2[g][i2]), fg=sigf(zfv[i2]);
            const float gg=fmaxf(zgv[i2],0.f), og=sigf(zov[i2]);
            const float cn = fg*c2s[g][i2] + ig*gg; c2s[g][i2]=cn;
            const float hn = og*fmaxf(cn,0.f);
            unsigned short sa,sb; split2(hn,sa,sb);
            unsigned lo = (unsigned)sa | ((unsigned)sb<<16);
            unsigned ot = (unsigned)__shfl_xor((int)lo,1);
            if ((li&1)==0){
              *(unsigned*)&asp2[g][wp][0][row*AS2+ch] = (lo & 0xFFFFu) | (ot<<16);
              *(unsigned*)&asp2[g][wp][1][row*AS2+ch] = (lo>>16) | (ot & 0xFFFF0000u);
            }
          }
        }
      }
      if (doL1){  // gate1(s+1): zi=C0, zf=xor8(C0), zg=C1, zo=xor8(C1); li<8
        float zfv[4], zov[4];
#pragma unroll
        for (int i2=0;i2<4;++i2){
          zfv[i2]=__shfl_xor(C0[g][i2],8);
          zov[i2]=__shfl_xor(C1[g][i2],8);
        }
        if (li < 8){
          const int ch = wave*8 + li;
#pragma unroll
          for (int i2=0;i2<4;++i2){
            const int row = quad*4+i2;
            const float ig=sigf(C0[g][i2]), fg=sigf(zfv[i2]);
            const float gg=fmaxf(C1[g][i2],0.f), og=sigf(zov[i2]);
            const float cn = fg*c1s[g][i2] + ig*gg; c1s[g][i2]=cn;
            const float hn = og*fmaxf(cn,0.f);
            unsigned short sa,sb; split2(hn,sa,sb);
            unsigned lo = (unsigned)sa | ((unsigned)sb<<16);
            unsigned ot = (unsigned)__shfl_xor((int)lo,1);
            if ((li&1)==0){
              *(unsigned*)&asp1[g][wp][0][row*AS1+24+ch] = (lo & 0xFFFFu) | (ot<<16);
              *(unsigned*)&asp1[g][wp][1][row*AS1+24+ch] = (lo>>16) | (ot & 0xFFFF0000u);
            }
          }
        }
      }
    }
    if (doX){
      unsigned short a1,a2,d1,d2; split2(xv.x,a1,a2); split2(xv.y,d1,d2);
      *(unsigned*)&asp1[xg][wp][0][xrow*AS1+xf] = (unsigned)a1 | ((unsigned)d1<<16);
      *(unsigned*)&asp1[xg][wp][1][xrow*AS1+xf] = (unsigned)a2 | ((unsigned)d2<<16);
    }
    __syncthreads();
  }

  // ---- phase-B/C weights (loaded once, between phases) ----
  short8 W3a[2], W3b[2];                 // [ntile], K=32 = 1 kstep
#pragma unroll
  for (int nt=0; nt<2; ++nt){
    short8 v1, v2;
#pragma unroll
    for (int j=0; j<8; ++j){
      const int k = quad*8 + j;
      const int c = nt ? colA1 : colA0;
      float w = W3[k*256+c];
      unsigned short s1,s2; split2(w,s1,s2);
      v1[j]=(short)s1; v2[j]=(short)s2;
    }
    W3a[nt]=v1; W3b[nt]=v2;
  }
  short8 U3a[2][2], U3b[2][2];           // [ntile][ks], K=64
#pragma unroll
  for (int nt=0; nt<2; ++nt)
#pragma unroll
  for (int ks=0; ks<2; ++ks){
    short8 v1, v2;
#pragma unroll
    for (int j=0; j<8; ++j){
      const int k = ks*32 + quad*8 + j;
      const int c = nt ? colA1 : colA0;
      float w = U3[k*256+c];
      unsigned short s1,s2; split2(w,s1,s2);
      v1[j]=(short)s1; v2[j]=(short)s2;
    }
    U3a[nt][ks]=v1; U3b[nt][ks]=v2;
  }
  short8 Wda[2], Wdb[2];                 // dense, waves 0/1, cols wave*16+li
  const int dcol = wave*16 + li;
  const bool dW = (wave < 2), dOK = dW && (dcol < 24);
  const float bdv = dOK ? bd[dcol] : 0.f;
#pragma unroll
  for (int ks=0; ks<2; ++ks){
    short8 v1, v2;
#pragma unroll
    for (int j=0; j<8; ++j){
      const int k = ks*32 + quad*8 + j;
      float w = dOK ? Wd[k*24+dcol] : 0.f;
      unsigned short s1,s2; split2(w,s1,s2);
      v1[j]=(short)s1; v2[j]=(short)s2;
    }
    Wda[ks]=v1; Wdb[ks]=v2;
  }
  const float bi3A = b3[colA0], bi3B = b3[colA1];

  // ---- Phase B: ZR = b3 + z@W3 via MFMA, straight into C-layout regs ----
  f32x4 ZR0[2], ZR1[2];
#pragma unroll
  for (int g=0; g<2; ++g){
    f32x4 z0 = {bi3A,bi3A,bi3A,bi3A}, z1 = {bi3B,bi3B,bi3B,bi3B};
    const int ab = li*AS2 + quad*8;
    short8 A1 = *(const short8*)&asp2[g][0][0][ab];   // h2(TT-1) parity 0
    short8 A2 = *(const short8*)&asp2[g][0][1][ab];
    PROD3(z0, A1,A2, W3a[0],W3b[0])
    PROD3(z1, A1,A2, W3a[1],W3b[1])
    ZR0[g]=z0; ZR1[g]=z1;
  }
  float c3s[2][4] = {};

  // =================== Phase C: L3 + fused dense, ONE barrier per t ===================
#pragma unroll 1
  for (int s=-1; s<TT; ++s){
    const int rp = s & 1, wp = rp ^ 1;
    const bool doM = (s < TT-1);
    const bool doD = (s >= 0) && dW;
    f32x4 C0c[2], C1c[2], Cd[2];
#pragma unroll
    for (int g=0; g<2; ++g){
      if (doM){ C0c[g]=ZR0[g]; C1c[g]=ZR1[g]; }
      if (doD){ f32x4 d = {bdv,bdv,bdv,bdv}; Cd[g]=d; }
      if (s >= 0 && (doM || doD)){
#pragma unroll
        for (int ks=0; ks<2; ++ks){
          const int ab = li*AS3 + ks*32 + quad*8;
          short8 A1 = *(const short8*)&asp3[g][rp][0][ab];
          short8 A2 = *(const short8*)&asp3[g][rp][1][ab];
          if (doM){
            PROD3(C0c[g], A1,A2, U3a[0][ks],U3b[0][ks])
            PROD3(C1c[g], A1,A2, U3a[1][ks],U3b[1][ks])
          }
          if (doD){ PROD3(Cd[g], A1,A2, Wda[ks],Wdb[ks]) }
        }
      }
    }
#pragma unroll
    for (int g=0; g<2; ++g){
      if (doD && dcol < 24){
#pragma unroll
        for (int i2=0;i2<4;++i2)
          out[((size_t)(b0 + g*16 + quad*4+i2)*TT + s)*FF + dcol] = Cd[g][i2];
      }
      if (doM){  // gate3(s+1), same pattern as gate1
        float zfv[4], zov[4];
#pragma unroll
        for (int i2=0;i2<4;++i2){
          zfv[i2]=__shfl_xor(C0c[g][i2],8);
          zov[i2]=__shfl_xor(C1c[g][i2],8);
        }
        if (li < 8){
          const int ch = wave*8 + li;
#pragma unroll
          for (int i2=0;i2<4;++i2){
            const int row = quad*4+i2;
            const float ig=sigf(C0c[g][i2]), fg=sigf(zfv[i2]);
            const float gg=fmaxf(C1c[g][i2],0.f), og=sigf(zov[i2]);
            const float cn = fg*c3s[g][i2] + ig*gg; c3s[g][i2]=cn;
            const float hn = og*fmaxf(cn,0.f);
            unsigned short sa,sb; split2(hn,sa,sb);
            unsigned lo = (unsigned)sa | ((unsigned)sb<<16);
            unsigned ot = (unsigned)__shfl_xor((int)lo,1);
            if ((li&1)==0){
              *(unsigned*)&asp3[g][wp][0][row*AS3+ch] = (lo & 0xFFFFu) | (ot<<16);
              *(unsigned*)&asp3[g][wp][1][row*AS3+ch] = (lo>>16) | (ot & 0xFFFF0000u);
            }
          }
        }
      }
    }
    __syncthreads();
  }
}

extern "C" void kernel_launch(void* const* d_in, const int* in_sizes, int n_in,
                              void* d_out, int out_size, void* d_ws, size_t ws_size,
                              hipStream_t stream){
  const float* x  = (const float*)d_in[0];
  const float* W1 = (const float*)d_in[1];
  const float* U1 = (const float*)d_in[2];
  const float* b1 = (const float*)d_in[3];
  const float* W2 = (const float*)d_in[4];
  const float* U2 = (const float*)d_in[5];
  const float* b2 = (const float*)d_in[6];
  const float* W3 = (const float*)d_in[7];
  const float* U3 = (const float*)d_in[8];
  const float* b3 = (const float*)d_in[9];
  const float* Wd = (const float*)d_in[10];
  const float* bd = (const float*)d_in[11];
  float* out = (float*)d_out;
  (void)d_ws; (void)ws_size; (void)in_sizes; (void)n_in; (void)out_size;

  hipLaunchKernelGGL(ae_k, dim3(256), dim3(512), 0, stream,
                     x, W1, U1, b1, W2, U2, b2, W3, U3, b3, Wd, bd, out);
}

// Round 8
// 314.911 us; speedup vs baseline: 1.6061x; 1.6061x over previous
//
#include <hip/hip_runtime.h>
#include <cstdint>

#define BB 8192
#define TT 50
#define FF 24

typedef __attribute__((ext_vector_type(8))) short short8;
typedef __attribute__((ext_vector_type(4))) float f32x4;

__device__ __forceinline__ float sigf(float x){ return 1.0f/(1.0f + __expf(-x)); }

// 2-way bf16 split (truncation): w ~= s1 + s2 to ~16 mantissa bits
__device__ __forceinline__ void split2(float w, unsigned short& s1, unsigned short& s2){
  unsigned b = __float_as_uint(w);
  s1 = (unsigned short)(b >> 16);
  float r = w - __uint_as_float(b & 0xFFFF0000u);
  s2 = (unsigned short)(__float_as_uint(r) >> 16);
}

#define MFMA(A,B,C) __builtin_amdgcn_mfma_f32_16x16x32_bf16((A),(B),(C),0,0,0)
#define PROD3(C,A1,A2,Bq1,Bq2) \
  C = MFMA(A1,Bq1,C); C = MFMA(A1,Bq2,C); C = MFMA(A2,Bq1,C);

// Round 8: round-6 structure (2 barriers/t, wave-specialized gates, LDS z
// round-trip -- round 7's in-register shfl gates regressed 1.5x) split into
// TWO kernels so each fits the (512,4) 128-reg/wave budget WITHOUT the
// round-6 scratch spill (~85 MB). h2 final state passes via 1 MB workspace.
// MFMA maps (verified m89): A[m=lane&15][k=quad*8+j], B[k][n=lane&15],
// C: col=lane&15, row=quad*4+reg. Biases folded into MFMA C-init.

// ---------------- ae_A: L1 + L2 -> h2ws[B][32] ----------------
// 512 blocks x 512 thr, 16 rows/block. Pipelined: seg(t) =
// {gate1(t) on waves 0-3 || gate2(t-1)+x(t+2)-stage on waves 4-7} barrier
// {MFMA2(t) + MFMA1(t+1)} barrier.
__global__ __launch_bounds__(512,4) void ae_A(
    const float* __restrict__ x,
    const float* __restrict__ W1, const float* __restrict__ U1, const float* __restrict__ b1,
    const float* __restrict__ W2, const float* __restrict__ U2, const float* __restrict__ b2,
    float* __restrict__ h2ws)
{
  constexpr int AS1 = 104, AS2 = 40, ZS1 = 260, ZS2 = 132;
  __shared__ __align__(16) unsigned short asp1[2][16*AS1]; // [x(24)|h1(64)|pad]
  __shared__ __align__(16) unsigned short asp2[2][16*AS2]; // [h2(32)|pad]
  __shared__ __align__(16) float zs1[16*ZS1];
  __shared__ __align__(16) float zs2[16*ZS2];

  const int tid = threadIdx.x, wave = tid>>6, lane = tid&63;
  const int quad = lane>>4, li = lane&15;
  const int b0 = blockIdx.x*16;

  short8 B1a[2][3], B1b[2][3];
#pragma unroll
  for (int nt=0; nt<2; ++nt)
#pragma unroll
  for (int ks=0; ks<3; ++ks){
    short8 v1, v2;
#pragma unroll
    for (int j=0; j<8; ++j){
      const int k = ks*32 + quad*8 + j;
      const int c = wave*32 + nt*16 + li;
      float w = (k<24) ? W1[k*256+c] : ((k<88) ? U1[(k-24)*256+c] : 0.f);
      unsigned short s1,s2; split2(w,s1,s2);
      v1[j]=(short)s1; v2[j]=(short)s2;
    }
    B1a[nt][ks]=v1; B1b[nt][ks]=v2;
  }
  short8 B2a[3], B2b[3];
#pragma unroll
  for (int ks=0; ks<3; ++ks){
    short8 v1, v2;
#pragma unroll
    for (int j=0; j<8; ++j){
      const int k = ks*32 + quad*8 + j;
      const int c = wave*16 + li;
      float w = (k<64) ? W2[k*128+c] : U2[(k-64)*128+c];
      unsigned short s1,s2; split2(w,s1,s2);
      v1[j]=(short)s1; v2[j]=(short)s2;
    }
    B2a[ks]=v1; B2b[ks]=v2;
  }
  const float bi1A = b1[wave*32+li], bi1B = b1[wave*32+16+li];
  const float bi2  = b2[wave*16+li];

  for (int i=tid; i<16*AS1; i+=512) ((unsigned int*)asp1)[i] = 0u;
  for (int i=tid; i<16*AS2; i+=512) ((unsigned int*)asp2)[i] = 0u;
  __syncthreads();
  if (tid < 16*FF){
    int r = tid/FF, f = tid - r*FF;
    unsigned short s1,s2; split2(x[((size_t)(b0+r)*TT + 0)*FF + f], s1,s2);
    asp1[0][r*AS1+f]=s1; asp1[1][r*AS1+f]=s2;
  }
  float c1_[4] = {0.f,0.f,0.f,0.f};
  float c2_[2] = {0.f,0.f};
  __syncthreads();

  // prologue: MFMA1(0) -> zs1
  {
    f32x4 C0 = {bi1A,bi1A,bi1A,bi1A}, C1v = {bi1B,bi1B,bi1B,bi1B};
#pragma unroll
    for (int ks=0; ks<3; ++ks){
      const int ab = li*AS1 + ks*32 + quad*8;
      short8 A1 = *(const short8*)&asp1[0][ab];
      short8 A2 = *(const short8*)&asp1[1][ab];
      PROD3(C0,  A1,A2, B1a[0][ks],B1b[0][ks])
      PROD3(C1v, A1,A2, B1a[1][ks],B1b[1][ks])
    }
#pragma unroll
    for (int i2=0; i2<4; ++i2){
      zs1[(quad*4+i2)*ZS1 + wave*32 + li]      = C0[i2];
      zs1[(quad*4+i2)*ZS1 + wave*32 + 16 + li] = C1v[i2];
    }
  }
  __syncthreads();

#pragma unroll 1
  for (int t=0; t<TT; ++t){
    // gate phase
    if (wave < 4){
      const int row = tid>>4, c0 = 4*(tid&15);
      float4 zi = *(float4*)&zs1[row*ZS1 +       c0];
      float4 zf = *(float4*)&zs1[row*ZS1 +  64 + c0];
      float4 zg = *(float4*)&zs1[row*ZS1 + 128 + c0];
      float4 zo = *(float4*)&zs1[row*ZS1 + 192 + c0];
      float h[4];
      { float ig=sigf(zi.x), fg=sigf(zf.x), gg=fmaxf(zg.x,0.f), og=sigf(zo.x);
        float cn=fg*c1_[0]+ig*gg; c1_[0]=cn; h[0]=og*fmaxf(cn,0.f); }
      { float ig=sigf(zi.y), fg=sigf(zf.y), gg=fmaxf(zg.y,0.f), og=sigf(zo.y);
        float cn=fg*c1_[1]+ig*gg; c1_[1]=cn; h[1]=og*fmaxf(cn,0.f); }
      { float ig=sigf(zi.z), fg=sigf(zf.z), gg=fmaxf(zg.z,0.f), og=sigf(zo.z);
        float cn=fg*c1_[2]+ig*gg; c1_[2]=cn; h[2]=og*fmaxf(cn,0.f); }
      { float ig=sigf(zi.w), fg=sigf(zf.w), gg=fmaxf(zg.w,0.f), og=sigf(zo.w);
        float cn=fg*c1_[3]+ig*gg; c1_[3]=cn; h[3]=og*fmaxf(cn,0.f); }
      unsigned bb0=__float_as_uint(h[0]), bb1=__float_as_uint(h[1]);
      unsigned bb2=__float_as_uint(h[2]), bb3=__float_as_uint(h[3]);
      uint2 P0 = { (bb0>>16)|(bb1&0xFFFF0000u), (bb2>>16)|(bb3&0xFFFF0000u) };
      unsigned rb0=__float_as_uint(h[0]-__uint_as_float(bb0&0xFFFF0000u));
      unsigned rb1=__float_as_uint(h[1]-__uint_as_float(bb1&0xFFFF0000u));
      unsigned rb2=__float_as_uint(h[2]-__uint_as_float(bb2&0xFFFF0000u));
      unsigned rb3=__float_as_uint(h[3]-__uint_as_float(bb3&0xFFFF0000u));
      uint2 P1 = { (rb0>>16)|(rb1&0xFFFF0000u), (rb2>>16)|(rb3&0xFFFF0000u) };
      *(uint2*)&asp1[0][row*AS1 + 24 + c0] = P0;
      *(uint2*)&asp1[1][row*AS1 + 24 + c0] = P1;
    } else {
      const int tid2 = tid - 256;
      if (t > 0){
        const int row = tid2>>4, c0 = 2*(tid2&15);
        float2 zi = *(float2*)&zs2[row*ZS2 +      c0];
        float2 zf = *(float2*)&zs2[row*ZS2 + 32 + c0];
        float2 zg = *(float2*)&zs2[row*ZS2 + 64 + c0];
        float2 zo = *(float2*)&zs2[row*ZS2 + 96 + c0];
        float h0, h1v;
        { float ig=sigf(zi.x), fg=sigf(zf.x), gg=fmaxf(zg.x,0.f), og=sigf(zo.x);
          float cn=fg*c2_[0]+ig*gg; c2_[0]=cn; h0=og*fmaxf(cn,0.f); }
        { float ig=sigf(zi.y), fg=sigf(zf.y), gg=fmaxf(zg.y,0.f), og=sigf(zo.y);
          float cn=fg*c2_[1]+ig*gg; c2_[1]=cn; h1v=og*fmaxf(cn,0.f); }
        unsigned ba=__float_as_uint(h0), bb=__float_as_uint(h1v);
        unsigned p0 = (ba>>16) | (bb & 0xFFFF0000u);
        float ra = h0  - __uint_as_float(ba & 0xFFFF0000u);
        float rb = h1v - __uint_as_float(bb & 0xFFFF0000u);
        unsigned p1 = (__float_as_uint(ra)>>16) | (__float_as_uint(rb) & 0xFFFF0000u);
        *(unsigned*)&asp2[0][row*AS2 + c0] = p0;
        *(unsigned*)&asp2[1][row*AS2 + c0] = p1;
      }
      if (t+1 < TT){
#pragma unroll
        for (int e=0; e<2; ++e){
          const int i = tid2 + 256*e;
          if (i < 16*FF){
            int r = i/FF, f = i - r*FF;
            unsigned short s1,s2;
            split2(x[((size_t)(b0+r)*TT + (t+1))*FF + f], s1,s2);
            asp1[0][r*AS1+f]=s1; asp1[1][r*AS1+f]=s2;
          }
        }
      }
    }
    __syncthreads();
    // MFMA phase: MFMA2(t) + MFMA1(t+1)
    {
      f32x4 C2 = {bi2,bi2,bi2,bi2};
#pragma unroll
      for (int ks=0; ks<2; ++ks){
        const int ab = li*AS1 + 24 + ks*32 + quad*8;
        short8 A1 = *(const short8*)&asp1[0][ab];
        short8 A2 = *(const short8*)&asp1[1][ab];
        PROD3(C2, A1,A2, B2a[ks],B2b[ks])
      }
      {
        const int ab = li*AS2 + quad*8;
        short8 A1 = *(const short8*)&asp2[0][ab];
        short8 A2 = *(const short8*)&asp2[1][ab];
        PROD3(C2, A1,A2, B2a[2],B2b[2])
      }
#pragma unroll
      for (int i2=0; i2<4; ++i2) zs2[(quad*4+i2)*ZS2 + wave*16 + li] = C2[i2];
    }
    if (t+1 < TT){
      f32x4 C0 = {bi1A,bi1A,bi1A,bi1A}, C1v = {bi1B,bi1B,bi1B,bi1B};
#pragma unroll
      for (int ks=0; ks<3; ++ks){
        const int ab = li*AS1 + ks*32 + quad*8;
        short8 A1 = *(const short8*)&asp1[0][ab];
        short8 A2 = *(const short8*)&asp1[1][ab];
        PROD3(C0,  A1,A2, B1a[0][ks],B1b[0][ks])
        PROD3(C1v, A1,A2, B1a[1][ks],B1b[1][ks])
      }
#pragma unroll
      for (int i2=0; i2<4; ++i2){
        zs1[(quad*4+i2)*ZS1 + wave*32 + li]      = C0[i2];
        zs1[(quad*4+i2)*ZS1 + wave*32 + 16 + li] = C1v[i2];
      }
    }
    __syncthreads();
  }
  // epilogue: gate2(TT-1) -> h2 -> workspace (fp32)
  if (wave >= 4){
    const int tid2 = tid - 256;
    const int row = tid2>>4, c0 = 2*(tid2&15);
    float2 zi = *(float2*)&zs2[row*ZS2 +      c0];
    float2 zf = *(float2*)&zs2[row*ZS2 + 32 + c0];
    float2 zg = *(float2*)&zs2[row*ZS2 + 64 + c0];
    float2 zo = *(float2*)&zs2[row*ZS2 + 96 + c0];
    float2 hv;
    { float ig=sigf(zi.x), fg=sigf(zf.x), gg=fmaxf(zg.x,0.f), og=sigf(zo.x);
      float cn=fg*c2_[0]+ig*gg; hv.x=og*fmaxf(cn,0.f); }
    { float ig=sigf(zi.y), fg=sigf(zf.y), gg=fmaxf(zg.y,0.f), og=sigf(zo.y);
      float cn=fg*c2_[1]+ig*gg; hv.y=og*fmaxf(cn,0.f); }
    *(float2*)&h2ws[(size_t)(b0+row)*32 + c0] = hv;
  }
}

// ---------------- ae_C: L3 + fused dense -> out[B][T][24] ----------------
// 512 blocks x 512 thr, 16 rows/block. ZR = b3 + h2@W3 via MFMA, held in
// C-layout registers; peeled t=0 gate via one zs1 round-trip; then round-6
// phase-C loop (2 barriers/t), dense rides on waves 0/1.
__global__ __launch_bounds__(512,4) void ae_C(
    const float* __restrict__ h2ws,
    const float* __restrict__ W3, const float* __restrict__ U3, const float* __restrict__ b3,
    const float* __restrict__ Wd, const float* __restrict__ bd,
    float* __restrict__ out)
{
  constexpr int AS2 = 40, AS3 = 72, ZS1 = 260;
  __shared__ __align__(16) unsigned short asp2[2][16*AS2]; // h2(32)|pad
  __shared__ __align__(16) unsigned short asp3[2][16*AS3]; // h3(64)|pad
  __shared__ __align__(16) float zs1[16*ZS1];

  const int tid = threadIdx.x, wave = tid>>6, lane = tid&63;
  const int quad = lane>>4, li = lane&15;
  const int b0 = blockIdx.x*16;

  // U3 B-frags
  short8 B3a[2][2], B3b[2][2];
#pragma unroll
  for (int nt=0; nt<2; ++nt)
#pragma unroll
  for (int ks=0; ks<2; ++ks){
    short8 v1, v2;
#pragma unroll
    for (int j=0; j<8; ++j){
      const int k = ks*32 + quad*8 + j;
      const int c = wave*32 + nt*16 + li;
      float w = U3[k*256+c];
      unsigned short s1,s2; split2(w,s1,s2);
      v1[j]=(short)s1; v2[j]=(short)s2;
    }
    B3a[nt][ks]=v1; B3b[nt][ks]=v2;
  }
  // W3 B-frags (K=32, one kstep)
  short8 W3a[2], W3b[2];
#pragma unroll
  for (int nt=0; nt<2; ++nt){
    short8 v1, v2;
#pragma unroll
    for (int j=0; j<8; ++j){
      const int k = quad*8 + j;
      const int c = wave*32 + nt*16 + li;
      float w = W3[k*256+c];
      unsigned short s1,s2; split2(w,s1,s2);
      v1[j]=(short)s1; v2[j]=(short)s2;
    }
    W3a[nt]=v1; W3b[nt]=v2;
  }
  // dense B-frags on waves 0/1
  short8 Bda[2], Bdb[2];
  const int dcol = wave*16 + li;
  const bool dW = (wave < 2), dOK = dW && (dcol < 24);
  const float bdv = dOK ? bd[dcol] : 0.f;
#pragma unroll
  for (int ks=0; ks<2; ++ks){
    short8 v1, v2;
#pragma unroll
    for (int j=0; j<8; ++j){
      const int k = ks*32 + quad*8 + j;
      float w = dOK ? Wd[k*24+dcol] : 0.f;
      unsigned short s1,s2; split2(w,s1,s2);
      v1[j]=(short)s1; v2[j]=(short)s2;
    }
    Bda[ks]=v1; Bdb[ks]=v2;
  }
  const float bi3A = b3[wave*32+li], bi3B = b3[wave*32+16+li];

  // stage h2 splits
  {
    const int row = tid>>5, ch = tid&31;
    unsigned short s1,s2; split2(h2ws[(size_t)(b0+row)*32 + ch], s1,s2);
    asp2[0][row*AS2+ch]=s1; asp2[1][row*AS2+ch]=s2;
  }
  __syncthreads();

  // ZR = b3 + h2 @ W3 (MFMA, straight into C-layout regs) + stage to zs1
  float zr0[4], zr1[4];
  {
    f32x4 Z0 = {bi3A,bi3A,bi3A,bi3A}, Z1 = {bi3B,bi3B,bi3B,bi3B};
    const int ab = li*AS2 + quad*8;
    short8 A1 = *(const short8*)&asp2[0][ab];
    short8 A2 = *(const short8*)&asp2[1][ab];
    PROD3(Z0, A1,A2, W3a[0],W3b[0])
    PROD3(Z1, A1,A2, W3a[1],W3b[1])
#pragma unroll
    for (int i2=0; i2<4; ++i2){
      zr0[i2]=Z0[i2]; zr1[i2]=Z1[i2];
      zs1[(quad*4+i2)*ZS1 + wave*32 + li]      = Z0[i2];
      zs1[(quad*4+i2)*ZS1 + wave*32 + 16 + li] = Z1[i2];
    }
  }
  float c3_[2] = {0.f,0.f};
  __syncthreads();

  // peeled t=0: c3=0 -> cn = i*g
  {
    const int row = tid>>5, c0 = 2*(tid&31);
    float2 zi = *(float2*)&zs1[row*ZS1 +       c0];
    float2 zg = *(float2*)&zs1[row*ZS1 + 128 + c0];
    float2 zo = *(float2*)&zs1[row*ZS1 + 192 + c0];
    float h0, h1v;
    { float ig=sigf(zi.x), gg=fmaxf(zg.x,0.f), og=sigf(zo.x);
      float cn=ig*gg; c3_[0]=cn; h0=og*fmaxf(cn,0.f); }
    { float ig=sigf(zi.y), gg=fmaxf(zg.y,0.f), og=sigf(zo.y);
      float cn=ig*gg; c3_[1]=cn; h1v=og*fmaxf(cn,0.f); }
    unsigned ba=__float_as_uint(h0), bb=__float_as_uint(h1v);
    unsigned p0 = (ba>>16) | (bb & 0xFFFF0000u);
    float ra = h0  - __uint_as_float(ba & 0xFFFF0000u);
    float rb = h1v - __uint_as_float(bb & 0xFFFF0000u);
    unsigned p1 = (__float_as_uint(ra)>>16) | (__float_as_uint(rb) & 0xFFFF0000u);
    *(unsigned*)&asp3[0][row*AS3 + c0] = p0;
    *(unsigned*)&asp3[1][row*AS3 + c0] = p1;
  }
  __syncthreads();

#pragma unroll 1
  for (int t=1; t<TT; ++t){
    f32x4 C0 = {zr0[0],zr0[1],zr0[2],zr0[3]};
    f32x4 C1v = {zr1[0],zr1[1],zr1[2],zr1[3]};
    f32x4 Cd = {bdv,bdv,bdv,bdv};
#pragma unroll
    for (int ks=0; ks<2; ++ks){
      const int ab = li*AS3 + ks*32 + quad*8;
      short8 A1 = *(const short8*)&asp3[0][ab];
      short8 A2 = *(const short8*)&asp3[1][ab];
      PROD3(C0,  A1,A2, B3a[0][ks],B3b[0][ks])
      PROD3(C1v, A1,A2, B3a[1][ks],B3b[1][ks])
      if (dW){ PROD3(Cd, A1,A2, Bda[ks],Bdb[ks]) }
    }
#pragma unroll
    for (int i2=0; i2<4; ++i2){
      zs1[(quad*4+i2)*ZS1 + wave*32 + li]      = C0[i2];
      zs1[(quad*4+i2)*ZS1 + wave*32 + 16 + li] = C1v[i2];
    }
    if (dOK){
#pragma unroll
      for (int i2=0; i2<4; ++i2)
        out[((size_t)(b0+quad*4+i2)*TT + (t-1))*FF + dcol] = Cd[i2];
    }
    __syncthreads();
    {
      const int row = tid>>5, c0 = 2*(tid&31);
      float2 zi = *(float2*)&zs1[row*ZS1 +       c0];
      float2 zf = *(float2*)&zs1[row*ZS1 +  64 + c0];
      float2 zg = *(float2*)&zs1[row*ZS1 + 128 + c0];
      float2 zo = *(float2*)&zs1[row*ZS1 + 192 + c0];
      float h0, h1v;
      { float ig=sigf(zi.x), fg=sigf(zf.x), gg=fmaxf(zg.x,0.f), og=sigf(zo.x);
        float cn=fg*c3_[0]+ig*gg; c3_[0]=cn; h0=og*fmaxf(cn,0.f); }
      { float ig=sigf(zi.y), fg=sigf(zf.y), gg=fmaxf(zg.y,0.f), og=sigf(zo.y);
        float cn=fg*c3_[1]+ig*gg; c3_[1]=cn; h1v=og*fmaxf(cn,0.f); }
      unsigned ba=__float_as_uint(h0), bb=__float_as_uint(h1v);
      unsigned p0 = (ba>>16) | (bb & 0xFFFF0000u);
      float ra = h0  - __uint_as_float(ba & 0xFFFF0000u);
      float rb = h1v - __uint_as_float(bb & 0xFFFF0000u);
      unsigned p1 = (__float_as_uint(ra)>>16) | (__float_as_uint(rb) & 0xFFFF0000u);
      *(unsigned*)&asp3[0][row*AS3 + c0] = p0;
      *(unsigned*)&asp3[1][row*AS3 + c0] = p1;
    }
    __syncthreads();
  }
  // final dense (t = TT-1)
  if (dW){
    f32x4 Cd = {bdv,bdv,bdv,bdv};
#pragma unroll
    for (int ks=0; ks<2; ++ks){
      const int ab = li*AS3 + ks*32 + quad*8;
      short8 A1 = *(const short8*)&asp3[0][ab];
      short8 A2 = *(const short8*)&asp3[1][ab];
      PROD3(Cd, A1,A2, Bda[ks],Bdb[ks])
    }
    if (dcol < 24){
#pragma unroll
      for (int i2=0; i2<4; ++i2)
        out[((size_t)(b0+quad*4+i2)*TT + (TT-1))*FF + dcol] = Cd[i2];
    }
  }
}

extern "C" void kernel_launch(void* const* d_in, const int* in_sizes, int n_in,
                              void* d_out, int out_size, void* d_ws, size_t ws_size,
                              hipStream_t stream){
  const float* x  = (const float*)d_in[0];
  const float* W1 = (const float*)d_in[1];
  const float* U1 = (const float*)d_in[2];
  const float* b1 = (const float*)d_in[3];
  const float* W2 = (const float*)d_in[4];
  const float* U2 = (const float*)d_in[5];
  const float* b2 = (const float*)d_in[6];
  const float* W3 = (const float*)d_in[7];
  const float* U3 = (const float*)d_in[8];
  const float* b3 = (const float*)d_in[9];
  const float* Wd = (const float*)d_in[10];
  const float* bd = (const float*)d_in[11];
  float* out = (float*)d_out;
  float* h2ws = (float*)d_ws;                  // [B][32] = 1 MB

  hipLaunchKernelGGL(ae_A, dim3(512), dim3(512), 0, stream,
                     x, W1, U1, b1, W2, U2, b2, h2ws);
  hipLaunchKernelGGL(ae_C, dim3(512), dim3(512), 0, stream,
                     h2ws, W3, U3, b3, Wd, bd, out);
}